// Round 2
// baseline (644.744 us; speedup 1.0000x reference)
//
#include <hip/hip_runtime.h>
#include <math.h>

// B=8, T=2048 -> M = 16384 rows; V=4096; C=128; 2NB=128; NOPS=8
#define M_TOT 16384
#define V_DIM 4096
#define C_DIM 128

typedef __bf16 bf16;
typedef __bf16 bf16x8 __attribute__((ext_vector_type(8)));
typedef float f32x4 __attribute__((ext_vector_type(4)));

__device__ inline f32x4 zero4() { f32x4 z; z[0]=0.f; z[1]=0.f; z[2]=0.f; z[3]=0.f; return z; }

__device__ inline bf16 f2bf(float f) {
  union { float f; unsigned u; } a; a.f = f;
  unsigned r = (a.u + 0x7FFFu + ((a.u >> 16) & 1u)) >> 16;
  union { unsigned short s; bf16 b; } o; o.s = (unsigned short)r;
  return o.b;
}

__device__ inline bf16x8 cvt8(float4 a, float4 b) {
  bf16x8 r;
  r[0]=f2bf(a.x); r[1]=f2bf(a.y); r[2]=f2bf(a.z); r[3]=f2bf(a.w);
  r[4]=f2bf(b.x); r[5]=f2bf(b.y); r[6]=f2bf(b.z); r[7]=f2bf(b.w);
  return r;
}

// async global->LDS, 16B per lane. LDS dest is wave-uniform base + lane*16.
__device__ inline void gld_lds16(const void* g, void* l) {
  __builtin_amdgcn_global_load_lds((const __attribute__((address_space(1))) void*)g,
                                   (__attribute__((address_space(3))) void*)l, 16, 0, 0);
}

// ---------------------------------------------------------------------------
// k_prep: fused {logits, w2, ops-transpose} (unchanged, proven)
// blocks 0..31   : LT[c][v] = rc[c,:] . basis[v,:]      (fp32, MFMA)
// blocks 32..95  : W2[v][c] = basis[v,:] . wc[c,:]      (bf16, MFMA)
// blocks 96..607 : WTO[i][n][k] = op_weights[i][k][n]   (bf16 transpose)
// ---------------------------------------------------------------------------
union PrepU {
  struct { bf16 A[128][136]; bf16 B[128][136]; } lg;
  struct { bf16 A[64][136];  bf16 B[128][136]; } w2;
};

__global__ __launch_bounds__(256) void k_prep(const float* __restrict__ basis,
                                              const float* __restrict__ rc,
                                              const float* __restrict__ wc,
                                              const float* __restrict__ opw,
                                              float* __restrict__ LT,
                                              bf16* __restrict__ W2,
                                              bf16* __restrict__ WTO) {
  __shared__ __align__(16) PrepU pu;
  const int t = threadIdx.x;
  const int bid = blockIdx.x;
  const int lane = t & 63, wave = t >> 6, fm = lane & 15, quad = lane >> 4;

  if (bid < 32) {  // ----- logits -----
    const int v0 = bid * 128;
    {
      const int row = t >> 1, c0 = (t & 1) * 64;
      const float4* p = (const float4*)(rc + row * 128 + c0);
      bf16x8* d = (bf16x8*)&pu.lg.A[row][c0];
#pragma unroll
      for (int j = 0; j < 8; j++) { float4 a = p[2*j], b = p[2*j+1]; d[j] = cvt8(a, b); }
    }
    {
      const int row = t >> 1, c0 = (t & 1) * 64;
      const float4* p = (const float4*)(basis + (size_t)(v0 + row) * 128 + c0);
      bf16x8* d = (bf16x8*)&pu.lg.B[row][c0];
#pragma unroll
      for (int j = 0; j < 8; j++) { float4 a = p[2*j], b = p[2*j+1]; d[j] = cvt8(a, b); }
    }
    __syncthreads();

    f32x4 acc[2][8];
#pragma unroll
    for (int m = 0; m < 2; m++)
#pragma unroll
      for (int n = 0; n < 8; n++) acc[m][n] = zero4();

#pragma unroll
    for (int kk = 0; kk < 4; kk++) {
      bf16x8 af[2];
#pragma unroll
      for (int m = 0; m < 2; m++)
        af[m] = *(const bf16x8*)&pu.lg.A[wave * 32 + m * 16 + fm][kk * 32 + quad * 8];
#pragma unroll
      for (int nt = 0; nt < 8; nt++) {
        bf16x8 bfr = *(const bf16x8*)&pu.lg.B[nt * 16 + fm][kk * 32 + quad * 8];
#pragma unroll
        for (int m = 0; m < 2; m++)
          acc[m][nt] = __builtin_amdgcn_mfma_f32_16x16x32_bf16(af[m], bfr, acc[m][nt], 0, 0, 0);
      }
    }
#pragma unroll
    for (int m = 0; m < 2; m++)
#pragma unroll
      for (int nt = 0; nt < 8; nt++)
#pragma unroll
        for (int r = 0; r < 4; r++) {
          int c = wave * 32 + m * 16 + quad * 4 + r;
          LT[(size_t)c * V_DIM + v0 + nt * 16 + fm] = acc[m][nt][r];
        }
  } else if (bid < 96) {  // ----- w2 -----
    const int v0 = (bid - 32) * 64;
    {
      const int row = t >> 2, c0 = (t & 3) * 32;
      const float4* p = (const float4*)(basis + (size_t)(v0 + row) * 128 + c0);
      bf16x8* d = (bf16x8*)&pu.w2.A[row][c0];
#pragma unroll
      for (int j = 0; j < 4; j++) { float4 a = p[2*j], b = p[2*j+1]; d[j] = cvt8(a, b); }
    }
    {
      const int row = t >> 1, c0 = (t & 1) * 64;
      const float4* p = (const float4*)(wc + row * 128 + c0);
      bf16x8* d = (bf16x8*)&pu.w2.B[row][c0];
#pragma unroll
      for (int j = 0; j < 8; j++) { float4 a = p[2*j], b = p[2*j+1]; d[j] = cvt8(a, b); }
    }
    __syncthreads();

    f32x4 acc[8];
#pragma unroll
    for (int n = 0; n < 8; n++) acc[n] = zero4();
#pragma unroll
    for (int kk = 0; kk < 4; kk++) {
      bf16x8 af = *(const bf16x8*)&pu.w2.A[wave * 16 + fm][kk * 32 + quad * 8];
#pragma unroll
      for (int nt = 0; nt < 8; nt++) {
        bf16x8 bfr = *(const bf16x8*)&pu.w2.B[nt * 16 + fm][kk * 32 + quad * 8];
        acc[nt] = __builtin_amdgcn_mfma_f32_16x16x32_bf16(af, bfr, acc[nt], 0, 0, 0);
      }
    }
#pragma unroll
    for (int nt = 0; nt < 8; nt++)
#pragma unroll
      for (int r = 0; r < 4; r++) {
        int v = v0 + wave * 16 + quad * 4 + r;
        W2[v * 128 + nt * 16 + fm] = f2bf(acc[nt][r]);
      }
  } else {  // ----- ops transpose -----
    int idx = (bid - 96) * 256 + t;  // 131072 total
    int i = idx >> 14, rem = idx & 16383, n = rem >> 7, k = rem & 127;
    WTO[idx] = f2bf(opw[(i << 14) + k * 128 + n]);
  }
}

// ---------------------------------------------------------------------------
// k_softmax: RT[c][v] = softmax_v(LT[c][v])   (bf16), block per c (unchanged)
// ---------------------------------------------------------------------------
__global__ __launch_bounds__(256) void k_softmax(const float* __restrict__ LT,
                                                 bf16* __restrict__ RT) {
  const int c = blockIdx.x, t = threadIdx.x;
  __shared__ float red[256];
  const float* row = LT + (size_t)c * V_DIM;
  float e[16];
  float lmax = -3.0e38f;
#pragma unroll
  for (int j = 0; j < 16; j++) { e[j] = row[t + 256 * j]; lmax = fmaxf(lmax, e[j]); }
  red[t] = lmax;
  __syncthreads();
  for (int off = 128; off > 0; off >>= 1) {
    if (t < off) red[t] = fmaxf(red[t], red[t + off]);
    __syncthreads();
  }
  const float gmax = red[0];
  __syncthreads();
  float lsum = 0.f;
#pragma unroll
  for (int j = 0; j < 16; j++) { e[j] = __expf(e[j] - gmax); lsum += e[j]; }
  red[t] = lsum;
  __syncthreads();
  for (int off = 128; off > 0; off >>= 1) {
    if (t < off) red[t] += red[t + off];
    __syncthreads();
  }
  const float inv = 1.f / red[0];
#pragma unroll
  for (int j = 0; j < 16; j++)
    RT[(size_t)c * V_DIM + t + 256 * j] = f2bf(e[j] * inv);
}

// ---------------------------------------------------------------------------
// nonlinearities for the op bank
// ---------------------------------------------------------------------------
__device__ inline float apply_nonlin(int i, float v) {
  switch (i) {
    case 0: return v;
    case 1: return fmaxf(v, 0.f);
    case 2: return 0.5f * v * (1.f + erff(v * 0.70710678118654752f));
    case 3: return v * v;
    case 4: return -v;
    case 5: return fabsf(v);
    case 6: return tanhf(v);
    default: return 1.f / (1.f + __expf(-v));
  }
}

// ---------------------------------------------------------------------------
// k_main: FUSED gemm1 + opbank + gemm2. One block = 64 output rows end-to-end.
// grid 256 (= 1 block/CU), block 256 (4 waves), 87 KB LDS.
//   phase 1: vals[64][128] = x[rows] @ RT^T, K=4096 streamed, fp32 acc in regs.
//            B via gld_lds double-buffered XOR-swizzled (verbatim gemm1 v2),
//            A direct-to-reg per lane (rows are wave-private).
//   phase 2: res = sum_i w_i * nonlin_i(vals @ WTO[i] + b_i); WTO staged
//            32KB/op into padded LDS, double-buffered (verbatim opbank).
//   phase 3: out[rows][v] = scale * res @ W2^T; 32 n-tiles of 128, W2 staged
//            padded + double-buffered (verbatim gemm2 B-path), direct stores.
// Eliminates PART (32 MB) + VAL2 (8 MB) HBM round-trips and 3 launch ramps.
// ---------------------------------------------------------------------------
union MainU {
  bf16 B2[2][128][64];    // phase 1: RT k-tiles (linear, swizzle via src/read)  32 KB
  bf16 Bp[2][128][136];   // phase 2/3: WTO / W2 tiles (pad 136 -> 2-way free)  68 KB
};

__global__ __launch_bounds__(256, 1) void k_main(const float* __restrict__ x,
                                                 const bf16* __restrict__ RT,
                                                 const bf16* __restrict__ WTO,
                                                 const bf16* __restrict__ W2,
                                                 const float* __restrict__ op_logits,
                                                 const float* __restrict__ op_biases,
                                                 const float* __restrict__ p_scale,
                                                 float* __restrict__ out) {
  __shared__ __align__(16) MainU mu;
  __shared__ __align__(16) bf16 S[64][136];  // vals / res transposer (17 KB)
  const int t = threadIdx.x;
  const int m0 = blockIdx.x * 64;
  const int lane = t & 63, wave = t >> 6;
  const int fm = lane & 15, quad = lane >> 4;
  const int sw = (fm & 7) << 4;  // read-side XOR swizzle (bytes), phase 1

  // ===================== phase 1: vals = x @ RT^T =====================
  // B staging (RT): 16 chunks of 1KB per 64-k step, wave w owns chunks 4w..4w+3.
  const int c_row = wave * 32 + (lane >> 3);
  const int src_colbyte = ((lane & 7) * 16) ^ ((lane >> 3) << 4);
  const bf16* bp = RT + (size_t)c_row * V_DIM + (src_colbyte >> 1);
  // A: this lane's MFMA fragment rows/cols directly
  const float* xp = x + (size_t)(m0 + wave * 16 + fm) * V_DIM + quad * 8;

  f32x4 acc[8];
#pragma unroll
  for (int i = 0; i < 8; i++) acc[i] = zero4();

#define G1_ISSUE_B(buf, koff)                                                  \
  {                                                                            \
    _Pragma("unroll")                                                          \
    for (int jj = 0; jj < 4; jj++)                                             \
      gld_lds16(bp + (size_t)jj * 8 * V_DIM + (koff),                          \
                (char*)&mu.B2[buf][0][0] + (wave * 4 + jj) * 1024);            \
  }

#define G1_ISSUE_A(p0, p1, p2, p3, koff)                                       \
  {                                                                            \
    p0 = *(const float4*)(xp + (koff));                                        \
    p1 = *(const float4*)(xp + (koff) + 4);                                    \
    p2 = *(const float4*)(xp + (koff) + 32);                                   \
    p3 = *(const float4*)(xp + (koff) + 36);                                   \
  }

#define G1_COMPUTE(buf, p0, p1, p2, p3)                                        \
  {                                                                            \
    bf16x8 af0 = cvt8(p0, p1);                                                 \
    bf16x8 af1 = cvt8(p2, p3);                                                 \
    const char* bb = (const char*)&mu.B2[buf][0][0];                           \
    _Pragma("unroll")                                                          \
    for (int nt = 0; nt < 8; nt++) {                                           \
      const char* rp = bb + (nt * 16 + fm) * 128;                              \
      bf16x8 b0 = *(const bf16x8*)(rp + ((quad * 16) ^ sw));                   \
      bf16x8 b1 = *(const bf16x8*)(rp + ((64 + quad * 16) ^ sw));              \
      acc[nt] = __builtin_amdgcn_mfma_f32_16x16x32_bf16(af0, b0, acc[nt], 0, 0, 0); \
      acc[nt] = __builtin_amdgcn_mfma_f32_16x16x32_bf16(af1, b1, acc[nt], 0, 0, 0); \
    }                                                                          \
  }

  float4 aE0, aE1, aE2, aE3, aO0, aO1, aO2, aO3;

  G1_ISSUE_B(0, 0);
  G1_ISSUE_A(aE0, aE1, aE2, aE3, 0);

  for (int s = 0; s < 32; s++) {
    const int k0 = s * 128;
    __syncthreads();  // buf0 + aE ready (vmcnt drained); prev buf1 reads done
    G1_ISSUE_B(1, k0 + 64);
    G1_ISSUE_A(aO0, aO1, aO2, aO3, k0 + 64);
    G1_COMPUTE(0, aE0, aE1, aE2, aE3);
    __syncthreads();
    if (s < 31) {
      G1_ISSUE_B(0, k0 + 128);
      G1_ISSUE_A(aE0, aE1, aE2, aE3, k0 + 128);
    }
    G1_COMPUTE(1, aO0, aO1, aO2, aO3);
  }
#undef G1_ISSUE_B
#undef G1_ISSUE_A
#undef G1_COMPUTE

  // vals (fp32 C-frags) -> S (bf16, A-operand layout via LDS transpose)
#pragma unroll
  for (int nt = 0; nt < 8; nt++)
#pragma unroll
    for (int r = 0; r < 4; r++)
      S[wave * 16 + quad * 4 + r][nt * 16 + fm] = f2bf(acc[nt][r]);

  // softmax over op_logits (all threads, tiny)
  float w[8];
  {
    float lm = -3.0e38f;
#pragma unroll
    for (int i = 0; i < 8; i++) { w[i] = op_logits[i]; lm = fmaxf(lm, w[i]); }
    float ssum = 0.f;
#pragma unroll
    for (int i = 0; i < 8; i++) { w[i] = __expf(w[i] - lm); ssum += w[i]; }
    float inv = 1.f / ssum;
#pragma unroll
    for (int i = 0; i < 8; i++) w[i] *= inv;
  }

  // preload WTO[0] tile to regs (hides L2 latency under the barrier)
  const int brow = t >> 1, boff = (t & 1) * 64;
  uint4 pv[8];
  {
    const uint4* p = (const uint4*)(WTO + brow * 128 + boff);
#pragma unroll
    for (int j = 0; j < 8; j++) pv[j] = p[j];
  }

  __syncthreads();  // S visible; all B2 reads done (Bp aliases B2)

  // ===================== phase 2: op bank =====================
  bf16x8 af[4];
#pragma unroll
  for (int kk = 0; kk < 4; kk++)
    af[kk] = *(const bf16x8*)&S[wave * 16 + fm][kk * 32 + quad * 8];

  f32x4 res[8];
#pragma unroll
  for (int nt = 0; nt < 8; nt++) res[nt] = zero4();

#pragma unroll
  for (int i = 0; i < 8; i++) {
    {  // write staged tile (regs -> padded LDS), then prefetch next op
      uint4* d = (uint4*)&mu.Bp[i & 1][brow][boff];
#pragma unroll
      for (int j = 0; j < 8; j++) d[j] = pv[j];
    }
    if (i < 7) {
      const uint4* p = (const uint4*)(WTO + (i + 1) * 16384 + brow * 128 + boff);
#pragma unroll
      for (int j = 0; j < 8; j++) pv[j] = p[j];
    }
    __syncthreads();  // Bp[i&1] visible
#pragma unroll
    for (int nt = 0; nt < 8; nt++) {
      f32x4 h = zero4();
#pragma unroll
      for (int kk = 0; kk < 4; kk++) {
        bf16x8 bfr = *(const bf16x8*)&mu.Bp[i & 1][nt * 16 + fm][kk * 32 + quad * 8];
        h = __builtin_amdgcn_mfma_f32_16x16x32_bf16(af[kk], bfr, h, 0, 0, 0);
      }
      float bias = op_biases[i * 128 + nt * 16 + fm];
#pragma unroll
      for (int r = 0; r < 4; r++)
        res[nt][r] += w[i] * apply_nonlin(i, h[r] + bias);
    }
    __syncthreads();  // all reads of Bp[i&1] done before overwrite at i+2
  }

  // res (fp32 C-frags) -> S (bf16 A-operand layout)
#pragma unroll
  for (int nt = 0; nt < 8; nt++)
#pragma unroll
    for (int r = 0; r < 4; r++)
      S[wave * 16 + quad * 4 + r][nt * 16 + fm] = f2bf(res[nt][r]);

  // preload W2 tile 0
  {
    const uint4* p = (const uint4*)(W2 + brow * 128 + boff);
#pragma unroll
    for (int j = 0; j < 8; j++) pv[j] = p[j];
  }

  __syncthreads();  // res visible in S; op7's Bp reads done

  // ===================== phase 3: out = scale * res @ W2^T =====================
  bf16x8 af2[4];
#pragma unroll
  for (int kk = 0; kk < 4; kk++)
    af2[kk] = *(const bf16x8*)&S[wave * 16 + fm][kk * 32 + quad * 8];

  const float scale = *p_scale;

#pragma unroll 2
  for (int ti = 0; ti < 32; ti++) {
    {  // write staged W2 tile, prefetch next
      uint4* d = (uint4*)&mu.Bp[ti & 1][brow][boff];
#pragma unroll
      for (int j = 0; j < 8; j++) d[j] = pv[j];
    }
    if (ti < 31) {
      const uint4* p = (const uint4*)(W2 + ((size_t)(ti + 1) * 128 + brow) * 128 + boff);
#pragma unroll
      for (int j = 0; j < 8; j++) pv[j] = p[j];
    }
    __syncthreads();  // Bp[ti&1] visible
#pragma unroll
    for (int nt = 0; nt < 8; nt++) {
      f32x4 a2 = zero4();
#pragma unroll
      for (int kk = 0; kk < 4; kk++) {
        bf16x8 bfr = *(const bf16x8*)&mu.Bp[ti & 1][nt * 16 + fm][kk * 32 + quad * 8];
        a2 = __builtin_amdgcn_mfma_f32_16x16x32_bf16(af2[kk], bfr, a2, 0, 0, 0);
      }
#pragma unroll
      for (int r = 0; r < 4; r++)
        out[(size_t)(m0 + wave * 16 + quad * 4 + r) * V_DIM + ti * 128 + nt * 16 + fm] =
            a2[r] * scale;
    }
    __syncthreads();  // reads of Bp[ti&1] done before overwrite at ti+2
  }
}

// ---------------------------------------------------------------------------
// launch
// ---------------------------------------------------------------------------
extern "C" void kernel_launch(void* const* d_in, const int* in_sizes, int n_in,
                              void* d_out, int out_size, void* d_ws, size_t ws_size,
                              hipStream_t stream) {
  const float* x      = (const float*)d_in[0];
  const float* basis  = (const float*)d_in[1];
  const float* rc     = (const float*)d_in[2];
  const float* wc     = (const float*)d_in[3];
  const float* oplog  = (const float*)d_in[4];
  const float* opw    = (const float*)d_in[5];
  const float* opb    = (const float*)d_in[6];
  const float* oscale = (const float*)d_in[7];
  float* out = (float*)d_out;
  char* ws = (char*)d_ws;

  // workspace layout (~4.5 MB)
  float* LT  = (float*)(ws);                    // 2 MB   (C,V) fp32 logits
  bf16* RT   = (bf16*)(ws + 2097152);           // 1 MB   (C,V)
  bf16* W2   = (bf16*)(ws + 3145728);           // 1 MB   (V,C)
  bf16* WTO  = (bf16*)(ws + 4194304);           // 256 KB (8,n,k)

  k_prep   <<<608, 256, 0, stream>>>(basis, rc, wc, opw, LT, W2, WTO);
  k_softmax<<<C_DIM, 256, 0, stream>>>(LT, RT);
  k_main   <<<M_TOT / 64, 256, 0, stream>>>(x, RT, WTO, W2, oplog, opb, oscale, out);
}